// Round 11
// baseline (129.066 us; speedup 1.0000x reference)
//
#include <hip/hip_runtime.h>
#include <math.h>

#define CEPS 1e-9f

typedef _Float16 half8 __attribute__((ext_vector_type(8)));
typedef float floatx16 __attribute__((ext_vector_type(16)));
typedef float f32x2 __attribute__((ext_vector_type(2)));
typedef float f32x4 __attribute__((ext_vector_type(4)));

// x  : [4,56,56,8,32] fp32    W: [4,4,128,32] fp32    bias: [128] fp32
// out: [4,112,112,128] fp32 act
//
// votes[b'][pix][m=(pixl,i)][ca] = sum_{tap,ci} xf[...]*W[kh][kw][ca][ci]
// xf[b'][h][w][i][ci] = x[i&3][h][w][2b'+(i>>2)][ci]   (reference reshape scramble)
// Wave = M32 (4 pixels along v x 8 i), N=128 (4 tiles), K=128 (8 steps of 16).
// Block = 4 waves = 4x4 pixel tile, one parity (rh,rw), one b'.
// W staged by prep_w as f16 B-fragments in d_ws (16 KB/parity, L1-resident;
// R7: inline fp32 W fetch+convert cost ~45 us of L2-latency stall vs table).
// Routing: per-pixel LDS transpose (wave-local, no barrier) to lane=(c,i),
// a(16) in-register as f32x2[8] -> in-lane chains use v_pk_*_f32 (R11);
// i-sums pure DPP; fast rcp/rsq; softmax xor16 via ds_swizzle.
//
// OCCUPANCY: 124 live regs (60 arch + 64 acc) -> 4 waves/SIMD is the HW cap;
// R10 proved launch-bounds tweaks don't move it. LDS 33.5 KB -> 4 blocks/CU.
// REGISTER HISTORY: (256,6)->2.1GB spill (R3); R6's layout at (256,4)->400MB
// spill; current structure fits (256,4) with no spill (R10: WRITE 25 MB).
// scx layout [i][ca pad 132]: R10's [ca][i pad 9] had 4-way-conflicted scalar
// va reads (1.9M conflict cyc); [i][132] gives 4x ds_read_b128 per lane.

template<int CTRL>
__device__ __forceinline__ float dpp_add(float v) {
    return v + __int_as_float(__builtin_amdgcn_update_dpp(
        0, __float_as_int(v), CTRL, 0xF, 0xF, false));
}

// sum over the 8-lane group (lane bits 0..2), result in all 8 lanes — pure VALU
__device__ __forceinline__ float sum_i8(float v) {
    v = dpp_add<0xB1>(v);    // quad_perm [1,0,3,2] == xor1
    v = dpp_add<0x4E>(v);    // quad_perm [2,3,0,1] == xor2
    v = dpp_add<0x141>(v);   // row_half_mirror: cross-quad (valid after quad sums)
    return v;
}

__device__ __forceinline__ float4 sel4(bool c, float4 a, float4 b) {
    return make_float4(c ? a.x : b.x, c ? a.y : b.y, c ? a.z : b.z, c ? a.w : b.w);
}

// B[k][n] fragment table: idx = ((parity*8 + s)*4 + t)*64 + l -> 8 f16
__global__ __launch_bounds__(256) void prep_w(const float* __restrict__ Wt,
                                              _Float16* __restrict__ wb) {
    int idx = blockIdx.x * 256 + threadIdx.x;    // [0, 8192)
    int parity = idx >> 11;
    int s = (idx >> 8) & 7;
    int t = (idx >> 6) & 3;
    int l = idx & 63;
    int rh = parity >> 1, rw = parity & 1;
    int n = t * 32 + (l & 31);
    int h = l >> 5;
    int ci0 = ((s & 1) << 4) + (h << 3);
    int kh = ((s >> 2) << 1) + 1 - rh;
    int kw = (((s >> 1) & 1) << 1) + 1 - rw;
    const float* src = Wt + (((kh * 4 + kw) * 128 + n) << 5) + ci0;
    float4 w0 = *(const float4*)src;
    float4 w1 = *(const float4*)(src + 4);
    half8 hv;
    hv[0] = (_Float16)w0.x; hv[1] = (_Float16)w0.y;
    hv[2] = (_Float16)w0.z; hv[3] = (_Float16)w0.w;
    hv[4] = (_Float16)w1.x; hv[5] = (_Float16)w1.y;
    hv[6] = (_Float16)w1.z; hv[7] = (_Float16)w1.w;
    *(half8*)(wb + ((long)idx << 3)) = hv;
}

__global__ __launch_bounds__(256, 4) void caps_mfma(
    const float* __restrict__ x,
    const _Float16* __restrict__ wb,
    const float* __restrict__ bias,
    float* __restrict__ out)
{
    // x tile: [cell(5x5)][i(8)][ci padded 32->40] f16
    __shared__ _Float16 xt[25 * 8 * 40];       // 16000 B
    // per-wave vote-transpose scratch: [i(8)][ca(128) padded ->132] fp32
    __shared__ float scx[4][1056];             // 16896 B
    // bias staged [c][a padded 16->20]: aligned b64 broadcast reads
    __shared__ float bsh[160];                 // 640 B

    const int tid = threadIdx.x;
    const int tile = blockIdx.x;            // 0..195 : 14x14 tiles of 4x4 pixels
    const int tu = tile / 14, tv = tile - tu * 14;
    const int u0 = tu * 4, v0 = tv * 4;
    const int rh = blockIdx.y >> 1;         // p & 1
    const int rw = blockIdx.y & 1;          // q & 1
    const int bp = blockIdx.z;              // b'
    const _Float16* wsrc = wb + ((long)blockIdx.y << 14);   // parity slice, 16 KB

    if (tid < 128) bsh[(tid >> 4) * 20 + (tid & 15)] = bias[tid];

    // ---- stage x: fp32 -> f16 tile [ri(5)][rj(5)][i(8)][ci], zero-filled OOB ----
    #pragma unroll
    for (int it = 0; it < 4; ++it) {
        int idx = tid + (it << 8);
        if (idx < 800) {
            int cell = idx >> 5;            // 0..24
            int r = idx & 31;
            int i = r >> 2;
            int ci0 = (r & 3) << 3;
            int ri = cell / 5, rj = cell - ri * 5;
            int gi = u0 + rh - 1 + ri;
            int gj = v0 + rw - 1 + rj;
            float tmp[8] = {0.f, 0.f, 0.f, 0.f, 0.f, 0.f, 0.f, 0.f};
            if ((unsigned)gi < 56u && (unsigned)gj < 56u) {
                const float* src = x + (((i & 3) * 56 + gi) * 56 + gj) * 256
                                     + ((bp * 2 + (i >> 2)) << 5) + ci0;
                float4 a0 = *(const float4*)src;
                float4 a1 = *(const float4*)(src + 4);
                tmp[0] = a0.x; tmp[1] = a0.y; tmp[2] = a0.z; tmp[3] = a0.w;
                tmp[4] = a1.x; tmp[5] = a1.y; tmp[6] = a1.z; tmp[7] = a1.w;
            }
            half8 hv;
            #pragma unroll
            for (int j = 0; j < 8; ++j) hv[j] = (_Float16)tmp[j];
            *(half8*)(xt + (cell * 8 + i) * 40 + ci0) = hv;
        }
    }
    __syncthreads();

    const int l = tid & 63;
    const int w = tid >> 6;                 // wave = u-row within tile
    const int col = l & 31, h = l >> 5;
    const int invA = (l & 31) * 40 + (h << 3);

    floatx16 acc[4];
    #pragma unroll
    for (int t = 0; t < 4; ++t)
        #pragma unroll
        for (int j = 0; j < 16; ++j) acc[t][j] = 0.f;

    // ---- MFMA K-loop: 8 k-steps x 4 n-tiles; B-frags from L1-resident table ----
    #pragma unroll
    for (int s = 0; s < 8; ++s) {
        const int tkh = s >> 2;
        const int tkw = (s >> 1) & 1;
        const int row = w + 1 - tkh;
        const int aoff = (row * 5 + 1 - tkw) * 320 + ((s & 1) << 4) + invA;
        half8 af = *(const half8*)(xt + aoff);
        #pragma unroll
        for (int t = 0; t < 4; ++t) {
            half8 bf = *(const half8*)(wsrc + (((s * 4 + t) * 64 + l) << 3));
            acc[t] = __builtin_amdgcn_mfma_f32_32x32x16_f16(af, bf, acc[t], 0, 0, 0);
        }
    }

    // ---- routing: lane = (c = l>>3, i = l&7), a(16) in-register as f32x2[8] ----
    float* scb = &scx[w][0];                // wave-local, no barrier needed
    const int cI = l >> 3;
    const int iI = l & 7;

    #pragma unroll
    for (int pixl = 0; pixl < 4; ++pixl) {
        // transpose: C-layout -> [i][ca] (row stride 132); i = 4h + il
        #pragma unroll
        for (int t = 0; t < 4; ++t)
            #pragma unroll
            for (int il = 0; il < 4; ++il)
                scb[((h << 2) + il) * 132 + t * 32 + col] = acc[t][pixl * 4 + il];

        // read my (c,i) row: 4x ds_read_b128, conflict-light
        const float* rb = scb + iI * 132 + (cI << 4);
        f32x4 vq0 = *(const f32x4*)(rb);
        f32x4 vq1 = *(const f32x4*)(rb + 4);
        f32x4 vq2 = *(const f32x4*)(rb + 8);
        f32x4 vq3 = *(const f32x4*)(rb + 12);
        f32x2 va2[8];
        va2[0] = __builtin_shufflevector(vq0, vq0, 0, 1);
        va2[1] = __builtin_shufflevector(vq0, vq0, 2, 3);
        va2[2] = __builtin_shufflevector(vq1, vq1, 0, 1);
        va2[3] = __builtin_shufflevector(vq1, vq1, 2, 3);
        va2[4] = __builtin_shufflevector(vq2, vq2, 0, 1);
        va2[5] = __builtin_shufflevector(vq2, vq2, 2, 3);
        va2[6] = __builtin_shufflevector(vq3, vq3, 0, 1);
        va2[7] = __builtin_shufflevector(vq3, vq3, 2, 3);

        f32x2 bq2[8];
        #pragma unroll
        for (int j = 0; j < 8; ++j)
            bq2[j] = *(const f32x2*)(bsh + cI * 20 + (j << 1));

        f32x2 pre2[8];
        float lg = 0.f;

        // ---- round 0: route = 1/8 ----
        #pragma unroll
        for (int j = 0; j < 8; ++j) {
            f32x2 s2;
            s2.x = sum_i8(va2[j].x);
            s2.y = sum_i8(va2[j].y);
            pre2[j] = 0.125f * s2 + bq2[j];             // v_pk_fma_f32
        }
        {
            f32x2 nq2 = pre2[0] * pre2[0];
            #pragma unroll
            for (int j = 1; j < 8; ++j) nq2 += pre2[j] * pre2[j];
            float nq = nq2.x + nq2.y;
            float sc = nq * __builtin_amdgcn_rcpf(1.f + nq)
                          * __builtin_amdgcn_rsqf(nq + CEPS);
            #pragma unroll
            for (int j = 0; j < 8; ++j) pre2[j] *= sc;  // pre2 = act now
            f32x2 d2 = va2[0] * pre2[0];
            #pragma unroll
            for (int j = 1; j < 8; ++j) d2 += va2[j] * pre2[j];
            lg = d2.x + d2.y;                            // per-(i,c), no shuffle
        }

        // ---- rounds 1,2 ----
        #pragma unroll
        for (int r = 1; r < 3; ++r) {
            // softmax over c (lane bits 3..5); logits bounded, no max-sub
            float e = __expf(lg);
            float ss = dpp_add<0x128>(e);                // ror8 == xor8 (in-row)
            ss += __int_as_float(__builtin_amdgcn_ds_swizzle(
                      __float_as_int(ss), 0x401F));      // xor16
            ss += __shfl_xor(ss, 32);
            float route = e * __builtin_amdgcn_rcpf(ss);
            #pragma unroll
            for (int j = 0; j < 8; ++j) {
                f32x2 p2 = route * va2[j];               // v_pk_mul_f32
                f32x2 m2;
                m2.x = sum_i8(p2.x);
                m2.y = sum_i8(p2.y);
                pre2[j] = m2 + bq2[j];                   // v_pk_add_f32
            }
            f32x2 nq2 = pre2[0] * pre2[0];
            #pragma unroll
            for (int j = 1; j < 8; ++j) nq2 += pre2[j] * pre2[j];
            float nq = nq2.x + nq2.y;
            float sc = nq * __builtin_amdgcn_rcpf(1.f + nq)
                          * __builtin_amdgcn_rsqf(nq + CEPS);
            #pragma unroll
            for (int j = 0; j < 8; ++j) pre2[j] *= sc;   // act
            if (r < 2) {
                f32x2 d2 = va2[0] * pre2[0];
                #pragma unroll
                for (int j = 1; j < 8; ++j) d2 += va2[j] * pre2[j];
                lg += d2.x + d2.y;
            }
        }

        // ---- store: lanes i<4 each write one float4 quad -> fully coalesced ----
        float4 q0 = make_float4(pre2[0].x, pre2[0].y, pre2[1].x, pre2[1].y);
        float4 q1 = make_float4(pre2[2].x, pre2[2].y, pre2[3].x, pre2[3].y);
        float4 q2 = make_float4(pre2[4].x, pre2[4].y, pre2[5].x, pre2[5].y);
        float4 q3 = make_float4(pre2[6].x, pre2[6].y, pre2[7].x, pre2[7].y);
        float4 t0 = sel4((iI & 1) != 0, q1, q0);
        float4 t1 = sel4((iI & 1) != 0, q3, q2);
        float4 o4 = sel4((iI & 2) != 0, t1, t0);
        if (iI < 4) {
            const int p = ((u0 + w) << 1) + rh;
            const int q = ((v0 + pixl) << 1) + rw;
            *(float4*)(out + (((bp * 112 + p) * 112 + q) << 7) + cI * 16 + iI * 4) = o4;
        }
    }
}

extern "C" void kernel_launch(void* const* d_in, const int* in_sizes, int n_in,
                              void* d_out, int out_size, void* d_ws, size_t ws_size,
                              hipStream_t stream) {
    const float* x  = (const float*)d_in[0];
    const float* Wt = (const float*)d_in[1];
    const float* b  = (const float*)d_in[2];
    float* out = (float*)d_out;
    _Float16* wb = (_Float16*)d_ws;          // 4 parities x 16384 f16 = 64 KB

    prep_w<<<32, 256, 0, stream>>>(Wt, wb);
    dim3 grid(196, 4, 4);    // 14x14 4x4-pixel tiles, 4 parity classes, 4 b'
    caps_mfma<<<grid, 256, 0, stream>>>(x, wb, b, out);
}

// Round 12
// 115.152 us; speedup vs baseline: 1.1208x; 1.1208x over previous
//
#include <hip/hip_runtime.h>
#include <math.h>

#define CEPS 1e-9f

typedef _Float16 half8 __attribute__((ext_vector_type(8)));
typedef _Float16 h2 __attribute__((ext_vector_type(2)));
typedef __fp16 fp16x2 __attribute__((ext_vector_type(2)));
typedef float floatx16 __attribute__((ext_vector_type(16)));
typedef float f32x4v __attribute__((ext_vector_type(4)));

// x  : [4,56,56,8,32] fp32    W: [4,4,128,32] fp32    bias: [128] fp32
// out: [4,112,112,128] fp32 act
//
// votes[b'][pix][m=(pixl,i)][ca] = sum_{tap,ci} xf[...]*W[kh][kw][ca][ci]
// xf[b'][h][w][i][ci] = x[i&3][h][w][2b'+(i>>2)][ci]   (reference reshape scramble)
// Wave = M32 (4 pixels along v x 8 i), N=128 (4 tiles), K=128 (8 steps of 16).
// Block = 4 waves = 4x4 pixel tile, one parity (rh,rw), one b'.
// W staged by prep_w as f16 B-fragments in d_ws (16 KB/parity, L1-resident).
//
// R12: routing math in PACKED f16 (a-dim as h2[8]): v_pk_fma_f16 halves all
// in-lane chains; v_dot2_f32_f16 does norm/logit dots with fp32 accumulate.
// i-sums: DPP on the 32-bit container + pk_add (robust even if DPP-mov
// doesn't fuse). lg / nq / softmax stay fp32. Evidence: VALU busy pinned at
// ~46us across R8/R10/R11 f32 variants -> only data-width cuts issue count.
//
// REGISTER HISTORY: (256,6)->2.1GB spill (R3); R6 layout at (256,4)->400MB
// spill; R8-style fits (256,4) (R10/R11: WRITE 25MB). f16 va/pre frees ~16
// more regs.  scx [i][ca pad 132] from R11 (conflict-light b128 reads).

template<int CTRL>
__device__ __forceinline__ float dpp_add(float v) {
    return v + __int_as_float(__builtin_amdgcn_update_dpp(
        0, __float_as_int(v), CTRL, 0xF, 0xF, false));
}
template<int CTRL>
__device__ __forceinline__ h2 dpp_add_h2(h2 v) {
    int t = __builtin_amdgcn_update_dpp(
        0, __builtin_bit_cast(int, v), CTRL, 0xF, 0xF, false);
    return v + __builtin_bit_cast(h2, t);
}
// sum over the 8-lane i-group (lane bits 0..2), both f16 components in parallel
__device__ __forceinline__ h2 sum_i8_h2(h2 v) {
    v = dpp_add_h2<0xB1>(v);     // quad_perm xor1
    v = dpp_add_h2<0x4E>(v);     // quad_perm xor2
    v = dpp_add_h2<0x141>(v);    // row_half_mirror (cross-quad)
    return v;
}
__device__ __forceinline__ h2 pkrtz(float a, float b) {
    return __builtin_bit_cast(h2, __builtin_amdgcn_cvt_pkrtz(a, b));
}
__device__ __forceinline__ float fdot2(h2 a, h2 b, float c) {
    return __builtin_amdgcn_fdot2(__builtin_bit_cast(fp16x2, a),
                                  __builtin_bit_cast(fp16x2, b), c, false);
}
__device__ __forceinline__ h2 hsel(bool c, h2 a, h2 b) {
    int r = c ? __builtin_bit_cast(int, a) : __builtin_bit_cast(int, b);
    return __builtin_bit_cast(h2, r);
}

// B[k][n] fragment table: idx = ((parity*8 + s)*4 + t)*64 + l -> 8 f16
__global__ __launch_bounds__(256) void prep_w(const float* __restrict__ Wt,
                                              _Float16* __restrict__ wb) {
    int idx = blockIdx.x * 256 + threadIdx.x;    // [0, 8192)
    int parity = idx >> 11;
    int s = (idx >> 8) & 7;
    int t = (idx >> 6) & 3;
    int l = idx & 63;
    int rh = parity >> 1, rw = parity & 1;
    int n = t * 32 + (l & 31);
    int h = l >> 5;
    int ci0 = ((s & 1) << 4) + (h << 3);
    int kh = ((s >> 2) << 1) + 1 - rh;
    int kw = (((s >> 1) & 1) << 1) + 1 - rw;
    const float* src = Wt + (((kh * 4 + kw) * 128 + n) << 5) + ci0;
    float4 w0 = *(const float4*)src;
    float4 w1 = *(const float4*)(src + 4);
    half8 hv;
    hv[0] = (_Float16)w0.x; hv[1] = (_Float16)w0.y;
    hv[2] = (_Float16)w0.z; hv[3] = (_Float16)w0.w;
    hv[4] = (_Float16)w1.x; hv[5] = (_Float16)w1.y;
    hv[6] = (_Float16)w1.z; hv[7] = (_Float16)w1.w;
    *(half8*)(wb + ((long)idx << 3)) = hv;
}

__global__ __launch_bounds__(256, 4) void caps_mfma(
    const float* __restrict__ x,
    const _Float16* __restrict__ wb,
    const float* __restrict__ bias,
    float* __restrict__ out)
{
    // x tile: [cell(5x5)][i(8)][ci padded 32->40] f16
    __shared__ _Float16 xt[25 * 8 * 40];       // 16000 B
    // per-wave vote-transpose scratch: [i(8)][ca(128) padded ->132] fp32
    __shared__ float scx[4][1056];             // 16896 B

    const int tid = threadIdx.x;
    const int tile = blockIdx.x;            // 0..195 : 14x14 tiles of 4x4 pixels
    const int tu = tile / 14, tv = tile - tu * 14;
    const int u0 = tu * 4, v0 = tv * 4;
    const int rh = blockIdx.y >> 1;         // p & 1
    const int rw = blockIdx.y & 1;          // q & 1
    const int bp = blockIdx.z;              // b'
    const _Float16* wsrc = wb + ((long)blockIdx.y << 14);   // parity slice, 16 KB

    // ---- stage x: fp32 -> f16 tile [ri(5)][rj(5)][i(8)][ci], zero-filled OOB ----
    #pragma unroll
    for (int it = 0; it < 4; ++it) {
        int idx = tid + (it << 8);
        if (idx < 800) {
            int cell = idx >> 5;            // 0..24
            int r = idx & 31;
            int i = r >> 2;
            int ci0 = (r & 3) << 3;
            int ri = cell / 5, rj = cell - ri * 5;
            int gi = u0 + rh - 1 + ri;
            int gj = v0 + rw - 1 + rj;
            float tmp[8] = {0.f, 0.f, 0.f, 0.f, 0.f, 0.f, 0.f, 0.f};
            if ((unsigned)gi < 56u && (unsigned)gj < 56u) {
                const float* src = x + (((i & 3) * 56 + gi) * 56 + gj) * 256
                                     + ((bp * 2 + (i >> 2)) << 5) + ci0;
                float4 a0 = *(const float4*)src;
                float4 a1 = *(const float4*)(src + 4);
                tmp[0] = a0.x; tmp[1] = a0.y; tmp[2] = a0.z; tmp[3] = a0.w;
                tmp[4] = a1.x; tmp[5] = a1.y; tmp[6] = a1.z; tmp[7] = a1.w;
            }
            half8 hv;
            #pragma unroll
            for (int j = 0; j < 8; ++j) hv[j] = (_Float16)tmp[j];
            *(half8*)(xt + (cell * 8 + i) * 40 + ci0) = hv;
        }
    }
    __syncthreads();

    const int l = tid & 63;
    const int w = tid >> 6;                 // wave = u-row within tile
    const int col = l & 31, h = l >> 5;
    const int invA = (l & 31) * 40 + (h << 3);

    floatx16 acc[4];
    #pragma unroll
    for (int t = 0; t < 4; ++t)
        #pragma unroll
        for (int j = 0; j < 16; ++j) acc[t][j] = 0.f;

    // ---- MFMA K-loop: 8 k-steps x 4 n-tiles; B-frags from L1-resident table ----
    #pragma unroll
    for (int s = 0; s < 8; ++s) {
        const int tkh = s >> 2;
        const int tkw = (s >> 1) & 1;
        const int row = w + 1 - tkh;
        const int aoff = (row * 5 + 1 - tkw) * 320 + ((s & 1) << 4) + invA;
        half8 af = *(const half8*)(xt + aoff);
        #pragma unroll
        for (int t = 0; t < 4; ++t) {
            half8 bf = *(const half8*)(wsrc + (((s * 4 + t) * 64 + l) << 3));
            acc[t] = __builtin_amdgcn_mfma_f32_32x32x16_f16(af, bf, acc[t], 0, 0, 0);
        }
    }

    // ---- routing: lane = (c = l>>3, i = l&7); a(16) in-register as h2[8] ----
    float* scb = &scx[w][0];                // wave-local, no barrier needed
    const int cI = l >> 3;
    const int iI = l & 7;

    // bias as packed f16 pairs, loaded once (8 distinct addrs/wave -> L1)
    h2 bq2[8];
    {
        const float* bpt = bias + (cI << 4);
        float4 b0 = *(const float4*)bpt;
        float4 b1 = *(const float4*)(bpt + 4);
        float4 b2 = *(const float4*)(bpt + 8);
        float4 b3 = *(const float4*)(bpt + 12);
        bq2[0] = pkrtz(b0.x, b0.y); bq2[1] = pkrtz(b0.z, b0.w);
        bq2[2] = pkrtz(b1.x, b1.y); bq2[3] = pkrtz(b1.z, b1.w);
        bq2[4] = pkrtz(b2.x, b2.y); bq2[5] = pkrtz(b2.z, b2.w);
        bq2[6] = pkrtz(b3.x, b3.y); bq2[7] = pkrtz(b3.z, b3.w);
    }
    const h2 c0125 = pkrtz(0.125f, 0.125f);

    #pragma unroll
    for (int pixl = 0; pixl < 4; ++pixl) {
        // transpose: C-layout -> [i][ca] (row stride 132); i = 4h + il
        #pragma unroll
        for (int t = 0; t < 4; ++t)
            #pragma unroll
            for (int il = 0; il < 4; ++il)
                scb[((h << 2) + il) * 132 + t * 32 + col] = acc[t][pixl * 4 + il];

        // read my (c,i) row: 4x ds_read_b128, convert to 8 packed f16 pairs
        const float* rb = scb + iI * 132 + (cI << 4);
        f32x4v vq0 = *(const f32x4v*)(rb);
        f32x4v vq1 = *(const f32x4v*)(rb + 4);
        f32x4v vq2 = *(const f32x4v*)(rb + 8);
        f32x4v vq3 = *(const f32x4v*)(rb + 12);
        h2 va2[8];
        va2[0] = pkrtz(vq0.x, vq0.y); va2[1] = pkrtz(vq0.z, vq0.w);
        va2[2] = pkrtz(vq1.x, vq1.y); va2[3] = pkrtz(vq1.z, vq1.w);
        va2[4] = pkrtz(vq2.x, vq2.y); va2[5] = pkrtz(vq2.z, vq2.w);
        va2[6] = pkrtz(vq3.x, vq3.y); va2[7] = pkrtz(vq3.z, vq3.w);

        h2 pre2[8];
        float lg;

        // ---- round 0: route = 1/8 ----
        #pragma unroll
        for (int j = 0; j < 8; ++j) {
            h2 s2 = sum_i8_h2(va2[j]);
            pre2[j] = s2 * c0125 + bq2[j];           // v_pk_fma_f16
        }
        {
            float nq = fdot2(pre2[0], pre2[0], 0.f);
            #pragma unroll
            for (int j = 1; j < 8; ++j) nq = fdot2(pre2[j], pre2[j], nq);
            float sc = nq * __builtin_amdgcn_rcpf(1.f + nq)
                          * __builtin_amdgcn_rsqf(nq + CEPS);
            h2 sc2 = pkrtz(sc, sc);
            #pragma unroll
            for (int j = 0; j < 8; ++j) pre2[j] *= sc2;   // pre2 = act
            float d = fdot2(va2[0], pre2[0], 0.f);
            #pragma unroll
            for (int j = 1; j < 8; ++j) d = fdot2(va2[j], pre2[j], d);
            lg = d;                                   // per-(i,c), fp32
        }

        // ---- rounds 1,2 ----
        #pragma unroll
        for (int r = 1; r < 3; ++r) {
            // softmax over c (lane bits 3..5); logits bounded, no max-sub; fp32
            float e = __expf(lg);
            float ss = dpp_add<0x128>(e);             // ror8 == xor8 (in-row)
            ss += __int_as_float(__builtin_amdgcn_ds_swizzle(
                      __float_as_int(ss), 0x401F));   // xor16
            ss += __shfl_xor(ss, 32);
            float route = e * __builtin_amdgcn_rcpf(ss);
            h2 rt2 = pkrtz(route, route);
            #pragma unroll
            for (int j = 0; j < 8; ++j) {
                h2 p = sum_i8_h2(rt2 * va2[j]);       // pk_mul + packed i-sum
                pre2[j] = p + bq2[j];                 // v_pk_add_f16
            }
            float nq = fdot2(pre2[0], pre2[0], 0.f);
            #pragma unroll
            for (int j = 1; j < 8; ++j) nq = fdot2(pre2[j], pre2[j], nq);
            float sc = nq * __builtin_amdgcn_rcpf(1.f + nq)
                          * __builtin_amdgcn_rsqf(nq + CEPS);
            h2 sc2 = pkrtz(sc, sc);
            #pragma unroll
            for (int j = 0; j < 8; ++j) pre2[j] *= sc2;   // act
            if (r < 2) {
                float d = lg;
                #pragma unroll
                for (int j = 0; j < 8; ++j) d = fdot2(va2[j], pre2[j], d);
                lg = d;
            }
        }

        // ---- store: lanes i<4 each write one float4 quad -> fully coalesced ----
        if (iI < 4) {
            // quad q=iI covers pairs j0=2(iI&1)+4((iI>>1)&1), j0+1
            h2 h0 = hsel((iI & 2) != 0, pre2[4], pre2[0]);
            h2 h1 = hsel((iI & 2) != 0, pre2[5], pre2[1]);
            h2 h2_ = hsel((iI & 2) != 0, pre2[6], pre2[2]);
            h2 h3 = hsel((iI & 2) != 0, pre2[7], pre2[3]);
            h2 p0 = hsel((iI & 1) != 0, h2_, h0);
            h2 p1 = hsel((iI & 1) != 0, h3, h1);
            float4 o4 = make_float4((float)p0.x, (float)p0.y,
                                    (float)p1.x, (float)p1.y);
            const int p = ((u0 + w) << 1) + rh;
            const int q = ((v0 + pixl) << 1) + rw;
            *(float4*)(out + (((bp * 112 + p) * 112 + q) << 7) + cI * 16 + iI * 4) = o4;
        }
    }
}

extern "C" void kernel_launch(void* const* d_in, const int* in_sizes, int n_in,
                              void* d_out, int out_size, void* d_ws, size_t ws_size,
                              hipStream_t stream) {
    const float* x  = (const float*)d_in[0];
    const float* Wt = (const float*)d_in[1];
    const float* b  = (const float*)d_in[2];
    float* out = (float*)d_out;
    _Float16* wb = (_Float16*)d_ws;          // 4 parities x 16384 f16 = 64 KB

    prep_w<<<32, 256, 0, stream>>>(Wt, wb);
    dim3 grid(196, 4, 4);    // 14x14 4x4-pixel tiles, 4 parity classes, 4 b'
    caps_mfma<<<grid, 256, 0, stream>>>(x, wb, b, out);
}